// Round 17
// baseline (106.112 us; speedup 1.0000x reference)
//
#include <hip/hip_runtime.h>
#include <hip/hip_bf16.h>
#include <math.h>

#define NQ 900
#define NT 100
#define BS 16
#define NH 7
#define NC 16
#define NSLOT 16      // 4 chunks (kc) x 4 elems (e); column idx = 4*lane + 256*kc + e
#define MAXTREE 8192  // per-phase tree guard (no hang on bug)

// ---------- Stage 1a: sigmoid + transpose probs: [h,b,q,c] -> [h,b,c,q] ----------
__global__ __launch_bounds__(256) void sig_transpose_kernel(const float* __restrict__ logits,
                                                            float* __restrict__ probsT) {
    const int hb = blockIdx.x;                       // 0..NH*BS-1
    const float* src = logits + (size_t)hb * NQ * NC;
    float* dst = probsT + (size_t)hb * NC * NQ;
    __shared__ float tile[NC][NQ + 1];
    for (int e = threadIdx.x; e < NQ * NC; e += 256) {
        int q = e >> 4, c = e & 15;
        float x = src[e];
        tile[c][q] = 1.0f / (1.0f + expf(-x));       // same formula as R0 -> identical costT
    }
    __syncthreads();
    for (int c = 0; c < NC; ++c)
        for (int q = threadIdx.x; q < NQ; q += 256)
            dst[c * NQ + q] = tile[c][q];
}

// ---------- Stage 1b: cost matrix (transposed [b][t][q]); one block per (b,t) ----------
__global__ __launch_bounds__(256) void cost_kernel_bt(const float4* __restrict__ pboxes4,
                                                      const float4* __restrict__ tboxes4,
                                                      const int*    __restrict__ tlabels,
                                                      const float*  __restrict__ probsT,
                                                      float* __restrict__ costT) {
    const int bt = blockIdx.x;
    const int b = bt / NT, t = bt % NT;

    const float* prow[NH];
    #pragma unroll
    for (int h = 0; h < NH; ++h) {
        int lab = tlabels[(h * BS + b) * NT + t];          // uniform -> scalar load
        prow[h] = probsT + (size_t)((h * BS + b) * NC + lab) * NQ;
    }

    float4 tb = tboxes4[b * NT + t];
    float tx = tb.x, ty = tb.y, tw = tb.z, th = tb.w;
    float bx0 = tx - 0.5f * tw, by0 = ty - 0.5f * th;
    float bx1 = tx + 0.5f * tw, by1 = ty + 0.5f * th;
    float areaB = (bx1 - bx0) * (by1 - by0);

    for (int q = threadIdx.x; q < NQ; q += 256) {
        float4 pb = pboxes4[b * NQ + q];
        float px = pb.x, py = pb.y, pw = pb.z, ph = pb.w;

        float cost_bbox = fabsf(px - tx) + fabsf(py - ty) + fabsf(pw - tw) + fabsf(ph - th);

        float ax0 = px - 0.5f * pw, ay0 = py - 0.5f * ph;
        float ax1 = px + 0.5f * pw, ay1 = py + 0.5f * ph;
        float areaA = (ax1 - ax0) * (ay1 - ay0);
        float ltx = fmaxf(ax0, bx0), lty = fmaxf(ay0, by0);
        float rbx = fminf(ax1, bx1), rby = fminf(ay1, by1);
        float iw = fmaxf(rbx - ltx, 0.f), ih = fmaxf(rby - lty, 0.f);
        float inter = iw * ih;
        float uni = areaA + areaB - inter;
        float iou = inter / uni;
        float ex0 = fminf(ax0, bx0), ey0 = fminf(ay0, by0);
        float ex1 = fmaxf(ax1, bx1), ey1 = fmaxf(ay1, by1);
        float ew = fmaxf(ex1 - ex0, 0.f), eh = fmaxf(ey1 - ey0, 0.f);
        float earea = ew * eh;
        float giou = iou - (earea - uni) / earea;

        float ssum = 0.f;
        #pragma unroll
        for (int h = 0; h < NH; ++h) ssum += prow[h][q];   // coalesced in q

        costT[(b * NT + t) * NQ + q] = 5.0f * cost_bbox - 2.0f * ssum - 2.0f * giou;
    }
}

// ---------- Fallback stage 1 (ws too small): fused direct gather (R3-verified) ----------
__global__ __launch_bounds__(256) void cost_kernel_fb(const float*  __restrict__ logits,
                                                      const float4* __restrict__ pboxes4,
                                                      const float4* __restrict__ tboxes4,
                                                      const int*    __restrict__ tlabels,
                                                      float* __restrict__ costT) {
    const int bt = blockIdx.x;
    const int b = bt / NT, t = bt % NT;

    int lab[NH];
    #pragma unroll
    for (int h = 0; h < NH; ++h) lab[h] = tlabels[(h * BS + b) * NT + t];

    float4 tb = tboxes4[b * NT + t];
    float tx = tb.x, ty = tb.y, tw = tb.z, th = tb.w;
    float bx0 = tx - 0.5f * tw, by0 = ty - 0.5f * th;
    float bx1 = tx + 0.5f * tw, by1 = ty + 0.5f * th;
    float areaB = (bx1 - bx0) * (by1 - by0);

    for (int q = threadIdx.x; q < NQ; q += 256) {
        float4 pb = pboxes4[b * NQ + q];
        float px = pb.x, py = pb.y, pw = pb.z, ph = pb.w;

        float cost_bbox = fabsf(px - tx) + fabsf(py - ty) + fabsf(pw - tw) + fabsf(ph - th);

        float ax0 = px - 0.5f * pw, ay0 = py - 0.5f * ph;
        float ax1 = px + 0.5f * pw, ay1 = py + 0.5f * ph;
        float areaA = (ax1 - ax0) * (ay1 - ay0);
        float ltx = fmaxf(ax0, bx0), lty = fmaxf(ay0, by0);
        float rbx = fminf(ax1, bx1), rby = fminf(ay1, by1);
        float iw = fmaxf(rbx - ltx, 0.f), ih = fmaxf(rby - lty, 0.f);
        float inter = iw * ih;
        float uni = areaA + areaB - inter;
        float iou = inter / uni;
        float ex0 = fminf(ax0, bx0), ey0 = fminf(ay0, by0);
        float ex1 = fmaxf(ax1, bx1), ey1 = fmaxf(ay1, by1);
        float ew = fmaxf(ex1 - ex0, 0.f), eh = fmaxf(ey1 - ey0, 0.f);
        float earea = ew * eh;
        float giou = iou - (earea - uni) / earea;

        float ssum = 0.f;
        #pragma unroll
        for (int h = 0; h < NH; ++h) {
            float x = logits[(size_t)((h * BS + b) * NQ + q) * NC + lab[h]];
            ssum += 1.0f / (1.0f + expf(-x));
        }

        costT[(b * NT + t) * NQ + q] = 5.0f * cost_bbox - 2.0f * ssum - 2.0f * giou;
    }
}

// ---------- Stage 2: JV LSA, v=0 init, Dijkstra-form SAP tree, f32 (R14/R15 base) ----------
// R16 changes (work removal, eps-exact):
//  * gate-fold: scan computes cand = (cf + gate[s]) + duv with gate = -v (free),
//    +INF (used/invalid). One op less per slot; gate recomputed once per phase end.
//    (~1 ulp associativity change vs R15 -- covered by the R12 eps-optimality margin.)
//  * pack-once cross-lane argmin: after the lane tree, key = monotone(bv)<<32 | bj;
//    6-level u64 min butterfly replaces f32-butterfly + ballot + ffs + shfl chain.
//    u64 min == (exact f32 min, smallest j) -- numpy-faithful tie-break.
__global__ __launch_bounds__(64) void lsa_kernel(const float* __restrict__ costT,
                                                 int* __restrict__ out) {
    const int b = blockIdx.x;
    const int lane = threadIdx.x;
    const float* cost = costT + b * NT * NQ;   // [t][q]

    __shared__ float u_s[NT + 1];
    __shared__ int p_s[NQ + 1];        // column -> row (0 = free)
    __shared__ int way2[NSLOT][64];    // way, owner-lane layout (phase-end dump)
    __shared__ int p_w[NQ + 1];        // greedy atomicMin arena
    __shared__ int jmin_s[NT];
    __shared__ int listA[NT];
    __shared__ int r2c[NT];
    __shared__ int cnt_s;

    for (int j = lane; j <= NQ; j += 64) {
        p_s[j] = 0;
        p_w[j] = 0x7fffffff;
    }
    __syncthreads();

    // ---- row minima + argmin (v = 0); greedy claim via atomicMin ----
    bool lostA = false, lostB = false;
    #pragma unroll
    for (int pass = 0; pass < 2; ++pass) {
        int r = pass * 64 + lane;
        if (r < NT) {
            const float4* row4 = (const float4*)(cost + (size_t)r * NQ);
            float m0 = INFINITY, m1f = INFINITY, m2f = INFINITY, m3f = INFINITY;
            int i0 = 0, i1 = 0, i2 = 0, i3 = 0;
            #pragma unroll 5
            for (int q4 = 0; q4 < NQ / 4; ++q4) {
                float4 cv = row4[q4];
                if (cv.x < m0)  { m0 = cv.x;  i0 = 4 * q4; }
                if (cv.y < m1f) { m1f = cv.y; i1 = 4 * q4 + 1; }
                if (cv.z < m2f) { m2f = cv.z; i2 = 4 * q4 + 2; }
                if (cv.w < m3f) { m3f = cv.w; i3 = 4 * q4 + 3; }
            }
            float mv = m0; int mj = i0;
            if (m1f < mv || (m1f == mv && i1 < mj)) { mv = m1f; mj = i1; }
            if (m2f < mv || (m2f == mv && i2 < mj)) { mv = m2f; mj = i2; }
            if (m3f < mv || (m3f == mv && i3 < mj)) { mv = m3f; mj = i3; }
            u_s[r + 1] = mv;            // u = rowmin (exact f32); v stays 0
            jmin_s[r] = mj;
            atomicMin(&p_w[mj + 1], r + 1);
        }
    }
    __syncthreads();

    // resolve winners (deterministic: smallest row wins each contested column)
    {
        int rA = lane;
        int j = jmin_s[rA] + 1;
        if (p_w[j] == rA + 1) p_s[j] = rA + 1;
        else lostA = true;
    }
    if (lane < NT - 64) {
        int rB = 64 + lane;
        int j = jmin_s[rB] + 1;
        if (p_w[j] == rB + 1) p_s[j] = rB + 1;
        else lostB = true;
    }
    // deterministic ascending free-row list via ballot bit-scan
    unsigned long long mA = __ballot(lostA);
    unsigned long long mB = __ballot(lostB);
    if (lane == 0) {
        int n = 0;
        unsigned long long m = mA;
        while (m) { int l = __ffsll((unsigned long long)m) - 1; listA[n++] = l + 1; m &= m - 1; }
        m = mB;
        while (m) { int l = __ffsll((unsigned long long)m) - 1; listA[n++] = 64 + l + 1; m &= m - 1; }
        cnt_s = n;
    }
    __syncthreads();
    const int nfree = cnt_s;

    // lane-owned columns: slot s = 4*kc + e -> idx = 4*lane + 256*kc + e, j = idx+1
    float v[NSLOT], minv[NSLOT], upreg[NSLOT], dreg[NSLOT], gate[NSLOT];
    int preg[NSLOT], wayreg[NSLOT];
    int jof[NSLOT];                    // constant per-lane column index j(s)
    // kc=3 covers idx 768..899 -> valid lanes 0..32 only
    const unsigned invalid = (lane <= 32) ? 0u : 0xF000u;
    #pragma unroll
    for (int s = 0; s < NSLOT; ++s) {
        v[s] = 0.0f; dreg[s] = 0.0f; wayreg[s] = 0;
        gate[s] = ((invalid >> s) & 1u) ? INFINITY : 0.0f;   // gate = -v (=0) or +INF
        jof[s] = 1 + 4 * lane + 256 * (s >> 2) + (s & 3);
        int pr = 0;
        if (!((invalid >> s) & 1u)) pr = p_s[jof[s]];
        preg[s] = pr;
        upreg[s] = (pr > 0) ? u_s[pr] : 0.0f;
    }
    __syncthreads();

    // root-row prefetch registers
    float4 c4pre[4];
    if (nfree > 0) {
        const float4* r4 = (const float4*)(cost + (size_t)(listA[0] - 1) * NQ);
        #pragma unroll
        for (int kc = 0; kc < 3; ++kc) c4pre[kc] = r4[lane + 64 * kc];
        c4pre[3] = (lane <= 32) ? r4[lane + 192] : make_float4(0.f, 0.f, 0.f, 0.f);
    }

    // ---- Dijkstra-form SAP tree phases (f32, gate-folded scan, packed reduce) ----
    for (int ii = 0; ii < nfree; ++ii) {
        const int i = listA[ii];
        #pragma unroll
        for (int s = 0; s < NSLOT; ++s) minv[s] = INFINITY;
        unsigned used = invalid;
        int j0 = 0;
        int i0 = i;
        float u_i0 = u_s[i];
        const float u_root = u_i0;
        float d0 = 0.0f;
        float deltaf = 0.0f;
        int guard = 0;

        float4 c4[4];
        #pragma unroll
        for (int kc = 0; kc < 4; ++kc) c4[kc] = c4pre[kc];   // prefetched root row

        while (guard++ < MAXTREE) {
            // mark j0 used: owner lane records dist, poisons minv & gate with +INF
            if (j0 != 0) {
                int idx = j0 - 1;
                if (lane == ((idx >> 2) & 63)) {
                    int slot = ((idx >> 8) << 2) | (idx & 3);
                    used |= (1u << slot);
                    #pragma unroll
                    for (int s = 0; s < NSLOT; ++s)
                        if (s == slot) { dreg[s] = d0; minv[s] = INFINITY; gate[s] = INFINITY; }
                }
            }

            // scan: cand = (cf + gate[s]) + duv; pure-register, branchless, 5 ops/slot
            const float duv = d0 - u_i0;
            #pragma unroll
            for (int kc = 0; kc < 4; ++kc) {
                #pragma unroll
                for (int e = 0; e < 4; ++e) {
                    const int s = 4 * kc + e;
                    float cf = (e == 0) ? c4[kc].x : (e == 1) ? c4[kc].y
                             : (e == 2) ? c4[kc].z : c4[kc].w;
                    float cand = (cf + gate[s]) + duv;
                    bool imp = cand < minv[s];
                    minv[s] = imp ? cand : minv[s];
                    wayreg[s] = imp ? j0 : wayreg[s];
                }
            }

            // per-lane 16->1 argmin: log-depth pairwise tree (tie -> lower half ==
            // smaller j since j monotone in slot index)
            float tm[NSLOT]; int tj[NSLOT];
            #pragma unroll
            for (int s = 0; s < NSLOT; ++s) { tm[s] = minv[s]; tj[s] = jof[s]; }
            #pragma unroll
            for (int st = 8; st >= 1; st >>= 1) {
                #pragma unroll
                for (int s = 0; s < 8; ++s) {
                    if (s < st) {
                        if (tm[s + st] < tm[s]) { tm[s] = tm[s + st]; tj[s] = tj[s + st]; }
                    }
                }
            }

            // pack ONCE: key = (monotone(f32 bits) << 32) | j ; u64 min butterfly
            unsigned long long key;
            {
                unsigned mb = __float_as_uint(tm[0]);
                mb = (mb & 0x80000000u) ? ~mb : (mb | 0x80000000u);
                key = ((unsigned long long)mb << 32) | (unsigned)tj[0];
            }
            #pragma unroll
            for (int off = 1; off < 64; off <<= 1) {
                unsigned long long ok = __shfl_xor(key, off);
                if (ok < key) key = ok;
            }
            const int jwin = (int)(key & 0xFFFFFFFFull);
            unsigned vb = (unsigned)(key >> 32);
            vb = (vb & 0x80000000u) ? (vb ^ 0x80000000u) : ~vb;   // inverse map (bit-exact)
            const float vmin = __uint_as_float(vb);

            // next row + its u from winner-lane registers (no LDS on the chain)
            const int widx = jwin - 1;
            const int wlane = (widx >> 2) & 63;
            const int wslot = ((widx >> 8) << 2) | (widx & 3);
            int pb = 0; float ub2 = 0.0f;
            #pragma unroll
            for (int s = 0; s < NSLOT; ++s)
                if (s == wslot) { pb = preg[s]; ub2 = upreg[s]; }
            int i0n = __shfl(pb, wlane);
            float u_n = __shfl(ub2, wlane);

            j0 = jwin;
            d0 = vmin;
            if (i0n == 0) { deltaf = vmin; break; }
            i0 = i0n;
            u_i0 = u_n;

            // bottom fetch for next iteration
            const float4* crow4 = (const float4*)(cost + (size_t)(i0 - 1) * NQ);
            #pragma unroll
            for (int kc = 0; kc < 3; ++kc) c4[kc] = crow4[lane + 64 * kc];
            c4[3] = (lane <= 32) ? crow4[lane + 192] : make_float4(0.f, 0.f, 0.f, 0.f);
        }

        // ---- prefetch next phase's root row (independent of everything below) ----
        if (ii + 1 < nfree) {
            const float4* r4 = (const float4*)(cost + (size_t)(listA[ii + 1] - 1) * NQ);
            #pragma unroll
            for (int kc = 0; kc < 3; ++kc) c4pre[kc] = r4[lane + 64 * kc];
            c4pre[3] = (lane <= 32) ? r4[lane + 192] : make_float4(0.f, 0.f, 0.f, 0.f);
        }

        // ---- phase end: dump way to LDS, one-pass dual updates, augment, refresh ----
        #pragma unroll
        for (int s = 0; s < NSLOT; ++s) way2[s][lane] = wayreg[s];   // conflict-free
        #pragma unroll
        for (int s = 0; s < NSLOT; ++s) {
            if (((used >> s) & 1u) && !((invalid >> s) & 1u)) {
                v[s] += (dreg[s] - deltaf);                   // v decreases
                u_s[preg[s]] = upreg[s] + (deltaf - dreg[s]); // distinct rows
            }
        }
        // recompute gate for all valid slots (un-poison used; fold new v)
        #pragma unroll
        for (int s = 0; s < NSLOT; ++s)
            gate[s] = ((invalid >> s) & 1u) ? INFINITY : -v[s];
        if (lane == 0) u_s[i] = u_root + deltaf;              // root row
        __syncthreads();
        if (lane == 0) {
            int j = j0;
            while (j) {
                int idx = j - 1;
                int ol = (idx >> 2) & 63;
                int sl = ((idx >> 8) << 2) | (idx & 3);
                int jw = way2[sl][ol];
                p_s[j] = (jw == 0) ? i : p_s[jw];
                j = jw;
            }
        }
        __syncthreads();
        // refresh preg/upreg only for changed slots: used columns + final column j0
        #pragma unroll
        for (int s = 0; s < NSLOT; ++s) {
            if (!((invalid >> s) & 1u)) {
                if (((used >> s) & 1u) || (jof[s] == j0)) {
                    int pr = p_s[jof[s]];
                    preg[s] = pr;
                    upreg[s] = (pr > 0) ? u_s[pr] : 0.0f;
                }
            }
        }
    }

    // ---- row2col + stable-argsort ranks ----
    __syncthreads();
    for (int j = 1 + lane; j <= NQ; j += 64) {
        int pi = p_s[j];
        if (pi > 0) r2c[pi - 1] = j - 1;
    }
    __syncthreads();
    for (int t = lane; t < NT; t += 64) {
        int ccol = r2c[t];
        int rank = 0;
        for (int tt = 0; tt < NT; ++tt) rank += (r2c[tt] < ccol) ? 1 : 0;
        out[b * 2 * NT + rank] = ccol;         // out[b,0,rank] = pred idx
        out[b * 2 * NT + NT + rank] = t;       // out[b,1,rank] = target idx
    }
}

extern "C" void kernel_launch(void* const* d_in, const int* in_sizes, int n_in,
                              void* d_out, int out_size, void* d_ws, size_t ws_size,
                              hipStream_t stream) {
    const float* logits  = (const float*)d_in[0];  // (7,16,900,16)
    const float* pboxes  = (const float*)d_in[1];  // (16,900,4)
    const float* tboxes  = (const float*)d_in[2];  // (16,100,4)
    const int*   tlabels = (const int*)d_in[3];    // (7,16,100)
    int* out = (int*)d_out;                        // (16,2,100) int32
    float* costT = (float*)d_ws;                   // 1,440,000 floats = 5.76 MB

    const size_t costT_elems  = (size_t)BS * NT * NQ;
    const size_t probsT_elems = (size_t)NH * BS * NC * NQ;
    const size_t need = (costT_elems + probsT_elems) * sizeof(float);

    if (ws_size >= need) {
        float* probsT = costT + costT_elems;
        sig_transpose_kernel<<<NH * BS, 256, 0, stream>>>(logits, probsT);
        cost_kernel_bt<<<BS * NT, 256, 0, stream>>>((const float4*)pboxes,
                                                    (const float4*)tboxes, tlabels, probsT, costT);
    } else {
        cost_kernel_fb<<<BS * NT, 256, 0, stream>>>(logits, (const float4*)pboxes,
                                                    (const float4*)tboxes, tlabels, costT);
    }
    lsa_kernel<<<BS, 64, 0, stream>>>(costT, out);
}

// Round 18
// 103.237 us; speedup vs baseline: 1.0278x; 1.0278x over previous
//
#include <hip/hip_runtime.h>
#include <hip/hip_bf16.h>
#include <math.h>

#define NQ 900
#define NT 100
#define BS 16
#define NH 7
#define NC 16
#define NSLOT 16      // 4 chunks (kc) x 4 elems (e); column idx = 4*lane + 256*kc + e
#define MAXTREE 8192  // per-phase tree guard (no hang on bug)

// ---------- Stage 1a: sigmoid + transpose probs: [h,b,q,c] -> [h,b,c,q] ----------
__global__ __launch_bounds__(256) void sig_transpose_kernel(const float* __restrict__ logits,
                                                            float* __restrict__ probsT) {
    const int hb = blockIdx.x;                       // 0..NH*BS-1
    const float* src = logits + (size_t)hb * NQ * NC;
    float* dst = probsT + (size_t)hb * NC * NQ;
    __shared__ float tile[NC][NQ + 1];
    for (int e = threadIdx.x; e < NQ * NC; e += 256) {
        int q = e >> 4, c = e & 15;
        float x = src[e];
        tile[c][q] = 1.0f / (1.0f + expf(-x));       // same formula as R0 -> identical costT
    }
    __syncthreads();
    for (int c = 0; c < NC; ++c)
        for (int q = threadIdx.x; q < NQ; q += 256)
            dst[c * NQ + q] = tile[c][q];
}

// ---------- Stage 1b: cost matrix (transposed [b][t][q]); one block per (b,t) ----------
__global__ __launch_bounds__(256) void cost_kernel_bt(const float4* __restrict__ pboxes4,
                                                      const float4* __restrict__ tboxes4,
                                                      const int*    __restrict__ tlabels,
                                                      const float*  __restrict__ probsT,
                                                      float* __restrict__ costT) {
    const int bt = blockIdx.x;
    const int b = bt / NT, t = bt % NT;

    const float* prow[NH];
    #pragma unroll
    for (int h = 0; h < NH; ++h) {
        int lab = tlabels[(h * BS + b) * NT + t];          // uniform -> scalar load
        prow[h] = probsT + (size_t)((h * BS + b) * NC + lab) * NQ;
    }

    float4 tb = tboxes4[b * NT + t];
    float tx = tb.x, ty = tb.y, tw = tb.z, th = tb.w;
    float bx0 = tx - 0.5f * tw, by0 = ty - 0.5f * th;
    float bx1 = tx + 0.5f * tw, by1 = ty + 0.5f * th;
    float areaB = (bx1 - bx0) * (by1 - by0);

    for (int q = threadIdx.x; q < NQ; q += 256) {
        float4 pb = pboxes4[b * NQ + q];
        float px = pb.x, py = pb.y, pw = pb.z, ph = pb.w;

        float cost_bbox = fabsf(px - tx) + fabsf(py - ty) + fabsf(pw - tw) + fabsf(ph - th);

        float ax0 = px - 0.5f * pw, ay0 = py - 0.5f * ph;
        float ax1 = px + 0.5f * pw, ay1 = py + 0.5f * ph;
        float areaA = (ax1 - ax0) * (ay1 - ay0);
        float ltx = fmaxf(ax0, bx0), lty = fmaxf(ay0, by0);
        float rbx = fminf(ax1, bx1), rby = fminf(ay1, by1);
        float iw = fmaxf(rbx - ltx, 0.f), ih = fmaxf(rby - lty, 0.f);
        float inter = iw * ih;
        float uni = areaA + areaB - inter;
        float iou = inter / uni;
        float ex0 = fminf(ax0, bx0), ey0 = fminf(ay0, by0);
        float ex1 = fmaxf(ax1, bx1), ey1 = fmaxf(ay1, by1);
        float ew = fmaxf(ex1 - ex0, 0.f), eh = fmaxf(ey1 - ey0, 0.f);
        float earea = ew * eh;
        float giou = iou - (earea - uni) / earea;

        float ssum = 0.f;
        #pragma unroll
        for (int h = 0; h < NH; ++h) ssum += prow[h][q];   // coalesced in q

        costT[(b * NT + t) * NQ + q] = 5.0f * cost_bbox - 2.0f * ssum - 2.0f * giou;
    }
}

// ---------- Fallback stage 1 (ws too small): fused direct gather (R3-verified) ----------
__global__ __launch_bounds__(256) void cost_kernel_fb(const float*  __restrict__ logits,
                                                      const float4* __restrict__ pboxes4,
                                                      const float4* __restrict__ tboxes4,
                                                      const int*    __restrict__ tlabels,
                                                      float* __restrict__ costT) {
    const int bt = blockIdx.x;
    const int b = bt / NT, t = bt % NT;

    int lab[NH];
    #pragma unroll
    for (int h = 0; h < NH; ++h) lab[h] = tlabels[(h * BS + b) * NT + t];

    float4 tb = tboxes4[b * NT + t];
    float tx = tb.x, ty = tb.y, tw = tb.z, th = tb.w;
    float bx0 = tx - 0.5f * tw, by0 = ty - 0.5f * th;
    float bx1 = tx + 0.5f * tw, by1 = ty + 0.5f * th;
    float areaB = (bx1 - bx0) * (by1 - by0);

    for (int q = threadIdx.x; q < NQ; q += 256) {
        float4 pb = pboxes4[b * NQ + q];
        float px = pb.x, py = pb.y, pw = pb.z, ph = pb.w;

        float cost_bbox = fabsf(px - tx) + fabsf(py - ty) + fabsf(pw - tw) + fabsf(ph - th);

        float ax0 = px - 0.5f * pw, ay0 = py - 0.5f * ph;
        float ax1 = px + 0.5f * pw, ay1 = py + 0.5f * ph;
        float areaA = (ax1 - ax0) * (ay1 - ay0);
        float ltx = fmaxf(ax0, bx0), lty = fmaxf(ay0, by0);
        float rbx = fminf(ax1, bx1), rby = fminf(ay1, by1);
        float iw = fmaxf(rbx - ltx, 0.f), ih = fmaxf(rby - lty, 0.f);
        float inter = iw * ih;
        float uni = areaA + areaB - inter;
        float iou = inter / uni;
        float ex0 = fminf(ax0, bx0), ey0 = fminf(ay0, by0);
        float ex1 = fmaxf(ax1, bx1), ey1 = fmaxf(ay1, by1);
        float ew = fmaxf(ex1 - ex0, 0.f), eh = fmaxf(ey1 - ey0, 0.f);
        float earea = ew * eh;
        float giou = iou - (earea - uni) / earea;

        float ssum = 0.f;
        #pragma unroll
        for (int h = 0; h < NH; ++h) {
            float x = logits[(size_t)((h * BS + b) * NQ + q) * NC + lab[h]];
            ssum += 1.0f / (1.0f + expf(-x));
        }

        costT[(b * NT + t) * NQ + q] = 5.0f * cost_bbox - 2.0f * ssum - 2.0f * giou;
    }
}

// ---------- Stage 2: JV LSA, v=0 init, Dijkstra-form SAP tree, f32 (R14/R15, best) ----------
// Final configuration: bias-gated branchless scan (R14), f32 butterfly + ballot winner
// pick (R12), prefetch rotation (R15). All components verified in passing rounds.
__global__ __launch_bounds__(64) void lsa_kernel(const float* __restrict__ costT,
                                                 int* __restrict__ out) {
    const int b = blockIdx.x;
    const int lane = threadIdx.x;
    const float* cost = costT + b * NT * NQ;   // [t][q]

    __shared__ float u_s[NT + 1];
    __shared__ int p_s[NQ + 1];        // column -> row (0 = free)
    __shared__ int way2[NSLOT][64];    // way, owner-lane layout (phase-end dump)
    __shared__ int p_w[NQ + 1];        // greedy atomicMin arena
    __shared__ int jmin_s[NT];
    __shared__ int listA[NT];
    __shared__ int r2c[NT];
    __shared__ int cnt_s;

    for (int j = lane; j <= NQ; j += 64) {
        p_s[j] = 0;
        p_w[j] = 0x7fffffff;
    }
    __syncthreads();

    // ---- row minima + argmin (v = 0); greedy claim via atomicMin ----
    bool lostA = false, lostB = false;
    #pragma unroll
    for (int pass = 0; pass < 2; ++pass) {
        int r = pass * 64 + lane;
        if (r < NT) {
            const float4* row4 = (const float4*)(cost + (size_t)r * NQ);
            float m0 = INFINITY, m1f = INFINITY, m2f = INFINITY, m3f = INFINITY;
            int i0 = 0, i1 = 0, i2 = 0, i3 = 0;
            #pragma unroll 5
            for (int q4 = 0; q4 < NQ / 4; ++q4) {
                float4 cv = row4[q4];
                if (cv.x < m0)  { m0 = cv.x;  i0 = 4 * q4; }
                if (cv.y < m1f) { m1f = cv.y; i1 = 4 * q4 + 1; }
                if (cv.z < m2f) { m2f = cv.z; i2 = 4 * q4 + 2; }
                if (cv.w < m3f) { m3f = cv.w; i3 = 4 * q4 + 3; }
            }
            float mv = m0; int mj = i0;
            if (m1f < mv || (m1f == mv && i1 < mj)) { mv = m1f; mj = i1; }
            if (m2f < mv || (m2f == mv && i2 < mj)) { mv = m2f; mj = i2; }
            if (m3f < mv || (m3f == mv && i3 < mj)) { mv = m3f; mj = i3; }
            u_s[r + 1] = mv;            // u = rowmin (exact f32); v stays 0
            jmin_s[r] = mj;
            atomicMin(&p_w[mj + 1], r + 1);
        }
    }
    __syncthreads();

    // resolve winners (deterministic: smallest row wins each contested column)
    {
        int rA = lane;
        int j = jmin_s[rA] + 1;
        if (p_w[j] == rA + 1) p_s[j] = rA + 1;
        else lostA = true;
    }
    if (lane < NT - 64) {
        int rB = 64 + lane;
        int j = jmin_s[rB] + 1;
        if (p_w[j] == rB + 1) p_s[j] = rB + 1;
        else lostB = true;
    }
    // deterministic ascending free-row list via ballot bit-scan
    unsigned long long mA = __ballot(lostA);
    unsigned long long mB = __ballot(lostB);
    if (lane == 0) {
        int n = 0;
        unsigned long long m = mA;
        while (m) { int l = __ffsll((unsigned long long)m) - 1; listA[n++] = l + 1; m &= m - 1; }
        m = mB;
        while (m) { int l = __ffsll((unsigned long long)m) - 1; listA[n++] = 64 + l + 1; m &= m - 1; }
        cnt_s = n;
    }
    __syncthreads();
    const int nfree = cnt_s;

    // lane-owned columns: slot s = 4*kc + e -> idx = 4*lane + 256*kc + e, j = idx+1
    float v[NSLOT], minv[NSLOT], upreg[NSLOT], dreg[NSLOT], biasreg[NSLOT];
    int preg[NSLOT], wayreg[NSLOT];
    int jof[NSLOT];                    // constant per-lane column index j(s)
    // kc=3 covers idx 768..899 -> valid lanes 0..32 only
    const unsigned invalid = (lane <= 32) ? 0u : 0xF000u;
    #pragma unroll
    for (int s = 0; s < NSLOT; ++s) {
        v[s] = 0.0f; dreg[s] = 0.0f; wayreg[s] = 0;
        biasreg[s] = ((invalid >> s) & 1u) ? INFINITY : 0.0f;
        jof[s] = 1 + 4 * lane + 256 * (s >> 2) + (s & 3);
        int pr = 0;
        if (!((invalid >> s) & 1u)) pr = p_s[jof[s]];
        preg[s] = pr;
        upreg[s] = (pr > 0) ? u_s[pr] : 0.0f;
    }
    __syncthreads();

    // root-row prefetch registers
    float4 c4pre[4];
    if (nfree > 0) {
        const float4* r4 = (const float4*)(cost + (size_t)(listA[0] - 1) * NQ);
        #pragma unroll
        for (int kc = 0; kc < 3; ++kc) c4pre[kc] = r4[lane + 64 * kc];
        c4pre[3] = (lane <= 32) ? r4[lane + 192] : make_float4(0.f, 0.f, 0.f, 0.f);
    }

    // ---- Dijkstra-form SAP tree phases (f32, bias-gated scan, rotated fetch) ----
    for (int ii = 0; ii < nfree; ++ii) {
        const int i = listA[ii];
        #pragma unroll
        for (int s = 0; s < NSLOT; ++s) minv[s] = INFINITY;
        unsigned used = invalid;
        int j0 = 0;
        int i0 = i;
        float u_i0 = u_s[i];
        const float u_root = u_i0;
        float d0 = 0.0f;
        float deltaf = 0.0f;
        int guard = 0;

        float4 c4[4];
        #pragma unroll
        for (int kc = 0; kc < 4; ++kc) c4[kc] = c4pre[kc];   // prefetched root row

        while (guard++ < MAXTREE) {
            // mark j0 used: owner lane records dist, poisons minv & bias with +INF
            if (j0 != 0) {
                int idx = j0 - 1;
                if (lane == ((idx >> 2) & 63)) {
                    int slot = ((idx >> 8) << 2) | (idx & 3);
                    used |= (1u << slot);
                    #pragma unroll
                    for (int s = 0; s < NSLOT; ++s)
                        if (s == slot) { dreg[s] = d0; minv[s] = INFINITY; biasreg[s] = INFINITY; }
                }
            }

            // scan: cand = (cf + bias + duv) - v[s]; pure-register, branchless
            const float duv = d0 - u_i0;
            #pragma unroll
            for (int kc = 0; kc < 4; ++kc) {
                #pragma unroll
                for (int e = 0; e < 4; ++e) {
                    const int s = 4 * kc + e;
                    float cf = (e == 0) ? c4[kc].x : (e == 1) ? c4[kc].y
                             : (e == 2) ? c4[kc].z : c4[kc].w;
                    float cand = ((cf + biasreg[s]) + duv) - v[s];
                    bool imp = cand < minv[s];
                    minv[s] = imp ? cand : minv[s];
                    wayreg[s] = imp ? j0 : wayreg[s];
                }
            }

            // per-lane 16->1 argmin: log-depth pairwise tree (tie -> lower half ==
            // smaller j since j monotone in slot index)
            float tm[NSLOT]; int tj[NSLOT];
            #pragma unroll
            for (int s = 0; s < NSLOT; ++s) { tm[s] = minv[s]; tj[s] = jof[s]; }
            #pragma unroll
            for (int st = 8; st >= 1; st >>= 1) {
                #pragma unroll
                for (int s = 0; s < 8; ++s) {
                    if (s < st) {
                        if (tm[s + st] < tm[s]) { tm[s] = tm[s + st]; tj[s] = tj[s + st]; }
                    }
                }
            }
            const float bv = tm[0];
            const int bj = tj[0];

            // value-only f32 min butterfly + ballot winner pick (R12-verified)
            float vmin = bv;
            #pragma unroll
            for (int off = 1; off < 64; off <<= 1)
                vmin = fminf(vmin, __shfl_xor(vmin, off));
            unsigned long long tied = __ballot(bv == vmin);
            int wl = __ffsll((unsigned long long)tied) - 1;
            int jwin = __shfl(bj, wl);

            // next row + its u from winner-lane registers (no LDS on the chain)
            int bs = (((bj - 1) >> 8) << 2) | ((bj - 1) & 3);
            int pb = 0; float ub2 = 0.0f;
            #pragma unroll
            for (int s = 0; s < NSLOT; ++s)
                if (s == bs) { pb = preg[s]; ub2 = upreg[s]; }
            int i0n = __shfl(pb, wl);
            float u_n = __shfl(ub2, wl);

            j0 = jwin;
            d0 = vmin;
            if (i0n == 0) { deltaf = vmin; break; }
            i0 = i0n;
            u_i0 = u_n;

            // bottom fetch for next iteration (same dependency point as R14's top fetch)
            const float4* crow4 = (const float4*)(cost + (size_t)(i0 - 1) * NQ);
            #pragma unroll
            for (int kc = 0; kc < 3; ++kc) c4[kc] = crow4[lane + 64 * kc];
            c4[3] = (lane <= 32) ? crow4[lane + 192] : make_float4(0.f, 0.f, 0.f, 0.f);
        }

        // ---- prefetch next phase's root row (independent of everything below) ----
        if (ii + 1 < nfree) {
            const float4* r4 = (const float4*)(cost + (size_t)(listA[ii + 1] - 1) * NQ);
            #pragma unroll
            for (int kc = 0; kc < 3; ++kc) c4pre[kc] = r4[lane + 64 * kc];
            c4pre[3] = (lane <= 32) ? r4[lane + 192] : make_float4(0.f, 0.f, 0.f, 0.f);
        }

        // ---- phase end: dump way to LDS, one-pass dual updates, augment, refresh ----
        #pragma unroll
        for (int s = 0; s < NSLOT; ++s) way2[s][lane] = wayreg[s];   // conflict-free
        #pragma unroll
        for (int s = 0; s < NSLOT; ++s) {
            if (((used >> s) & 1u) && !((invalid >> s) & 1u)) {
                v[s] += (dreg[s] - deltaf);                   // v decreases
                u_s[preg[s]] = upreg[s] + (deltaf - dreg[s]); // distinct rows
                biasreg[s] = 0.0f;                            // un-poison
            }
        }
        if (lane == 0) u_s[i] = u_root + deltaf;              // root row
        __syncthreads();
        if (lane == 0) {
            int j = j0;
            while (j) {
                int idx = j - 1;
                int ol = (idx >> 2) & 63;
                int sl = ((idx >> 8) << 2) | (idx & 3);
                int jw = way2[sl][ol];
                p_s[j] = (jw == 0) ? i : p_s[jw];
                j = jw;
            }
        }
        __syncthreads();
        // refresh preg/upreg only for changed slots: used columns + final column j0
        #pragma unroll
        for (int s = 0; s < NSLOT; ++s) {
            if (!((invalid >> s) & 1u)) {
                if (((used >> s) & 1u) || (jof[s] == j0)) {
                    int pr = p_s[jof[s]];
                    preg[s] = pr;
                    upreg[s] = (pr > 0) ? u_s[pr] : 0.0f;
                }
            }
        }
    }

    // ---- row2col + stable-argsort ranks ----
    __syncthreads();
    for (int j = 1 + lane; j <= NQ; j += 64) {
        int pi = p_s[j];
        if (pi > 0) r2c[pi - 1] = j - 1;
    }
    __syncthreads();
    for (int t = lane; t < NT; t += 64) {
        int ccol = r2c[t];
        int rank = 0;
        for (int tt = 0; tt < NT; ++tt) rank += (r2c[tt] < ccol) ? 1 : 0;
        out[b * 2 * NT + rank] = ccol;         // out[b,0,rank] = pred idx
        out[b * 2 * NT + NT + rank] = t;       // out[b,1,rank] = target idx
    }
}

extern "C" void kernel_launch(void* const* d_in, const int* in_sizes, int n_in,
                              void* d_out, int out_size, void* d_ws, size_t ws_size,
                              hipStream_t stream) {
    const float* logits  = (const float*)d_in[0];  // (7,16,900,16)
    const float* pboxes  = (const float*)d_in[1];  // (16,900,4)
    const float* tboxes  = (const float*)d_in[2];  // (16,100,4)
    const int*   tlabels = (const int*)d_in[3];    // (7,16,100)
    int* out = (int*)d_out;                        // (16,2,100) int32
    float* costT = (float*)d_ws;                   // 1,440,000 floats = 5.76 MB

    const size_t costT_elems  = (size_t)BS * NT * NQ;
    const size_t probsT_elems = (size_t)NH * BS * NC * NQ;
    const size_t need = (costT_elems + probsT_elems) * sizeof(float);

    if (ws_size >= need) {
        float* probsT = costT + costT_elems;
        sig_transpose_kernel<<<NH * BS, 256, 0, stream>>>(logits, probsT);
        cost_kernel_bt<<<BS * NT, 256, 0, stream>>>((const float4*)pboxes,
                                                    (const float4*)tboxes, tlabels, probsT, costT);
    } else {
        cost_kernel_fb<<<BS * NT, 256, 0, stream>>>(logits, (const float4*)pboxes,
                                                    (const float4*)tboxes, tlabels, costT);
    }
    lsa_kernel<<<BS, 64, 0, stream>>>(costT, out);
}